// Round 2
// baseline (953.535 us; speedup 1.0000x reference)
//
#include <hip/hip_runtime.h>

typedef unsigned short u16;
typedef unsigned int u32;
typedef short bf16x8_t __attribute__((ext_vector_type(8)));
typedef float f32x4_t __attribute__((ext_vector_type(4)));

// ---------------- workspace layout (bytes) ----------------
#define OFF_XB   (0)
#define SZ_XB    (4096*416*2)
#define OFF_WCAT (OFF_XB + SZ_XB)
#define SZ_WCAT  (3072*416*2)
#define OFF_W2T  (OFF_WCAT + SZ_WCAT)
#define SZ_W2    (1024*1024*2)
#define OFF_W2I  (OFF_W2T + SZ_W2)
#define OFF_T1   (OFF_W2I + SZ_W2)
#define SZ_T1    (4096*1024*2)
#define OFF_P    (OFF_T1 + SZ_T1)
#define SZ_PQ    (4096*1024*4)
#define OFF_Q    (OFF_P + SZ_PQ)
// total ~49.7 MB

__device__ __forceinline__ u16 f2bf(float f) {
  union { float f; u32 u; } v; v.f = f;
  u32 r = v.u + 0x7fffu + ((v.u >> 16) & 1u);
  return (u16)(r >> 16);
}
// relu both, round-to-nearest via +0x8000 bias, pack hi16s with one v_perm_b32
__device__ __forceinline__ u32 pk2(float a, float b) {
  u32 ua = __float_as_uint(fmaxf(a, 0.f)) + 0x8000u;
  u32 ub = __float_as_uint(fmaxf(b, 0.f)) + 0x8000u;
  return __builtin_amdgcn_perm(ub, ua, 0x07060302);  // lo16=hi16(ua), hi16=hi16(ub)
}
__device__ __forceinline__ void gload_lds16(const void* g, void* l) {
  __builtin_amdgcn_global_load_lds(
      (const __attribute__((address_space(1))) void*)g,
      (__attribute__((address_space(3))) void*)l, 16, 0, 0);
}
// stage a 128-row x 32-col bf16 tile into lds[128][32] (row-major, unpadded)
__device__ __forceinline__ void stage128x32(const u16* g, int ld, int row0, int k0,
                                            u16* lds, int wave, int lane) {
#pragma unroll
  for (int it = 0; it < 2; ++it) {
    int rbase = it * 64 + wave * 16;
    const u16* src = g + (size_t)(row0 + rbase + (lane >> 2)) * ld + k0 + (lane & 3) * 8;
    gload_lds16(src, lds + rbase * 32);
  }
}

// ---------------- prep kernels ----------------
__global__ void k_prep_x(const float* __restrict__ x, u16* __restrict__ Xb) {
  int k = blockIdx.x * 256 + threadIdx.x;
  int r = blockIdx.y;
  if (k < 416)
    Xb[(size_t)r * 416 + k] = (k < 400) ? f2bf(x[(size_t)r * 400 + k]) : (u16)0;
}

__global__ void k_prep_wcat(const float* __restrict__ t1w, const float* __restrict__ i1w,
                            u16* __restrict__ Wt) {
  int k = blockIdx.x * 256 + threadIdx.x;
  int n = blockIdx.y;
  if (k >= 416) return;
  float v = 0.f;
  if (k < 400) {
    if (n < 1024)      v = t1w[(size_t)k * 1024 + n];
    else if (n < 2048) v = i1w[(size_t)k * 1024 + (n - 1024)];
    else               v = i1w[(size_t)(400 + k) * 1024 + (n - 2048)];
  }
  Wt[(size_t)n * 416 + k] = f2bf(v);
}

__global__ void k_transpose(const float* __restrict__ W, u16* __restrict__ Wt) {
  __shared__ float t[32][33];
  int k0 = blockIdx.y * 32, n0 = blockIdx.x * 32;
  int tx = threadIdx.x, ty = threadIdx.y;
#pragma unroll
  for (int i = 0; i < 32; i += 8)
    t[ty + i][tx] = W[(size_t)(k0 + ty + i) * 1024 + n0 + tx];
  __syncthreads();
#pragma unroll
  for (int i = 0; i < 32; i += 8)
    Wt[(size_t)(n0 + ty + i) * 1024 + k0 + tx] = f2bf(t[tx][ty + i]);
}

// ---------------- GEMM 1: Xb(4096x416) @ Wcat_t -> T1 | P' | Q ----------------
__global__ __launch_bounds__(256) void k_gemm_l1(
    const u16* __restrict__ Xb, const u16* __restrict__ Wt,
    const float* __restrict__ b_t1, const float* __restrict__ b_i1,
    u16* __restrict__ T1, float* __restrict__ Pp, float* __restrict__ Qq) {
  __shared__ __align__(16) u16 al[128 * 32];
  __shared__ __align__(16) u16 bl[128 * 32];
  int tid = threadIdx.x, lane = tid & 63, wave = tid >> 6;
  int wr = wave & 1, wc = wave >> 1, ln = lane & 15, quad = lane >> 4;
  int m0 = blockIdx.x * 128, n0 = blockIdx.y * 128;
  f32x4_t acc[4][4];
#pragma unroll
  for (int i = 0; i < 4; ++i)
#pragma unroll
    for (int j = 0; j < 4; ++j) acc[i][j] = (f32x4_t){0.f, 0.f, 0.f, 0.f};

  for (int k0 = 0; k0 < 416; k0 += 32) {
    stage128x32(Xb, 416, m0, k0, al, wave, lane);
    stage128x32(Wt, 416, n0, k0, bl, wave, lane);
    __syncthreads();
    bf16x8_t af[4], bfr[4];
#pragma unroll
    for (int mt = 0; mt < 4; ++mt)
      af[mt] = *(const bf16x8_t*)(al + (wr * 64 + mt * 16 + ln) * 32 + quad * 8);
#pragma unroll
    for (int nt = 0; nt < 4; ++nt)
      bfr[nt] = *(const bf16x8_t*)(bl + (wc * 64 + nt * 16 + ln) * 32 + quad * 8);
#pragma unroll
    for (int mt = 0; mt < 4; ++mt)
#pragma unroll
      for (int nt = 0; nt < 4; ++nt)
        acc[mt][nt] = __builtin_amdgcn_mfma_f32_16x16x32_bf16(af[mt], bfr[nt], acc[mt][nt], 0, 0, 0);
    __syncthreads();
  }
  int seg = n0 >> 10;  // 0: T1, 1: P'(+b1), 2: Q
#pragma unroll
  for (int nt = 0; nt < 4; ++nt) {
    int n_g = n0 + wc * 64 + nt * 16 + ln;
    int ns = n_g & 1023;
    float bias = (seg == 0) ? b_t1[ns] : (seg == 1 ? b_i1[ns] : 0.f);
#pragma unroll
    for (int mt = 0; mt < 4; ++mt) {
      f32x4_t c = acc[mt][nt];
#pragma unroll
      for (int r = 0; r < 4; ++r) {
        int m_g = m0 + wr * 64 + mt * 16 + quad * 4 + r;
        size_t idx = (size_t)m_g * 1024 + ns;
        float v = c[r] + bias;
        if (seg == 0)      T1[idx] = (u16)((__float_as_uint(fmaxf(v, 0.f)) + 0x8000u) >> 16);
        else if (seg == 1) Pp[idx] = v;
        else               Qq[idx] = v;
      }
    }
  }
}

// ---------------- traj layers 2+3 fused ----------------
__global__ __launch_bounds__(256) void k_traj23(
    const u16* __restrict__ T1, const u16* __restrict__ W2t,
    const float* __restrict__ b2, const float* __restrict__ w3,
    const float* __restrict__ b3, float* __restrict__ out) {
  __shared__ __align__(16) u16 al[128 * 32];
  __shared__ __align__(16) u16 bl[128 * 32];
  __shared__ float rowsum[128];
  int tid = threadIdx.x, lane = tid & 63, wave = tid >> 6;
  int wr = wave & 1, wc = wave >> 1, ln = lane & 15, quad = lane >> 4;
  int m0 = blockIdx.x * 128, n0 = blockIdx.y * 128;
  f32x4_t acc[4][4];
#pragma unroll
  for (int i = 0; i < 4; ++i)
#pragma unroll
    for (int j = 0; j < 4; ++j) acc[i][j] = (f32x4_t){0.f, 0.f, 0.f, 0.f};

  for (int k0 = 0; k0 < 1024; k0 += 32) {
    stage128x32(T1, 1024, m0, k0, al, wave, lane);
    stage128x32(W2t, 1024, n0, k0, bl, wave, lane);
    __syncthreads();
    bf16x8_t af[4], bfr[4];
#pragma unroll
    for (int mt = 0; mt < 4; ++mt)
      af[mt] = *(const bf16x8_t*)(al + (wr * 64 + mt * 16 + ln) * 32 + quad * 8);
#pragma unroll
    for (int nt = 0; nt < 4; ++nt)
      bfr[nt] = *(const bf16x8_t*)(bl + (wc * 64 + nt * 16 + ln) * 32 + quad * 8);
#pragma unroll
    for (int mt = 0; mt < 4; ++mt)
#pragma unroll
      for (int nt = 0; nt < 4; ++nt)
        acc[mt][nt] = __builtin_amdgcn_mfma_f32_16x16x32_bf16(af[mt], bfr[nt], acc[mt][nt], 0, 0, 0);
    __syncthreads();
  }
  float b2v[4], w3v[4];
#pragma unroll
  for (int nt = 0; nt < 4; ++nt) {
    int n = n0 + wc * 64 + nt * 16 + ln;
    b2v[nt] = b2[n]; w3v[nt] = w3[n];
  }
  if (tid < 128) rowsum[tid] = 0.f;
  __syncthreads();
#pragma unroll
  for (int mt = 0; mt < 4; ++mt) {
    float s[4] = {0.f, 0.f, 0.f, 0.f};
#pragma unroll
    for (int nt = 0; nt < 4; ++nt) {
      f32x4_t c = acc[mt][nt];
#pragma unroll
      for (int r = 0; r < 4; ++r) s[r] += fmaxf(c[r] + b2v[nt], 0.f) * w3v[nt];
    }
#pragma unroll
    for (int r = 0; r < 4; ++r) {
      for (int off = 1; off < 16; off <<= 1) s[r] += __shfl_xor(s[r], off);
      if (ln == 0) atomicAdd(&rowsum[wr * 64 + mt * 16 + quad * 4 + r], s[r]);
    }
  }
  __syncthreads();
  float contrib = 0.f;
  if (tid < 128) contrib = rowsum[tid] + (n0 == 0 ? b3[0] : 0.f);
  for (int off = 1; off < 32; off <<= 1) contrib += __shfl_xor(contrib, off);
  if ((lane & 31) == 0 && tid < 128) atomicAdd(&out[(m0 + tid) >> 5], contrib);
}

// ---------------- fused interaction kernel: 128x256 tile ----------------
#define LDA_H 40
__global__ __launch_bounds__(256) void k_int_fused(
    const float* __restrict__ Pp, const float* __restrict__ Qq,
    const u16* __restrict__ W2t, const float* __restrict__ b2,
    const float* __restrict__ w3, const float* __restrict__ b3,
    const float* __restrict__ edges, float* __restrict__ out) {
  __shared__ __align__(16) u16 h1[128 * LDA_H];
  __shared__ __align__(16) u16 bl[256 * 32];
  __shared__ float rowsum[128];
  int tid = threadIdx.x, lane = tid & 63, wave = tid >> 6;
  int wr = wave & 1, wc = wave >> 1, ln = lane & 15, quad = lane >> 4;
  int mtile = blockIdx.y;        // 0..1023
  int n0 = blockIdx.x * 256;     // n fastest -> co-resident blocks share P/Q in L2
  int b = mtile >> 3;
  int i0 = (mtile & 7) * 4;

  int rloc = tid >> 1;           // 0..127
  int kh = (tid & 1) * 16;       // 16 k's per thread
  const float* prow = Pp + ((size_t)(b * 32 + i0 + (rloc >> 5)) << 10);
  const float* qrow = Qq + ((size_t)(b * 32 + (rloc & 31)) << 10);

  f32x4_t acc[4][8];
#pragma unroll
  for (int i = 0; i < 4; ++i)
#pragma unroll
    for (int j = 0; j < 8; ++j) acc[i][j] = (f32x4_t){0.f, 0.f, 0.f, 0.f};

  for (int k0 = 0; k0 < 1024; k0 += 32) {
    const float4* pr = (const float4*)(prow + k0 + kh);
    const float4* qr = (const float4*)(qrow + k0 + kh);
    float4 p0 = pr[0], p1 = pr[1], p2 = pr[2], p3 = pr[3];
    float4 q0 = qr[0], q1 = qr[1], q2 = qr[2], q3 = qr[3];
    uint4 w0, w1;
    w0.x = pk2(p0.x + q0.x, p0.y + q0.y);
    w0.y = pk2(p0.z + q0.z, p0.w + q0.w);
    w0.z = pk2(p1.x + q1.x, p1.y + q1.y);
    w0.w = pk2(p1.z + q1.z, p1.w + q1.w);
    w1.x = pk2(p2.x + q2.x, p2.y + q2.y);
    w1.y = pk2(p2.z + q2.z, p2.w + q2.w);
    w1.z = pk2(p3.x + q3.x, p3.y + q3.y);
    w1.w = pk2(p3.z + q3.z, p3.w + q3.w);
    uint4* dst = (uint4*)(h1 + rloc * LDA_H + kh);
    dst[0] = w0; dst[1] = w1;
    // stage B tile: 256 rows x 32 cols
#pragma unroll
    for (int it = 0; it < 4; ++it) {
      int rbase = it * 64 + wave * 16;
      const u16* src = W2t + (size_t)(n0 + rbase + (lane >> 2)) * 1024 + k0 + (lane & 3) * 8;
      gload_lds16(src, bl + rbase * 32);
    }
    __syncthreads();
    bf16x8_t af[4], bfr[8];
#pragma unroll
    for (int mt = 0; mt < 4; ++mt)
      af[mt] = *(const bf16x8_t*)(h1 + (wr * 64 + mt * 16 + ln) * LDA_H + quad * 8);
#pragma unroll
    for (int nt = 0; nt < 8; ++nt)
      bfr[nt] = *(const bf16x8_t*)(bl + (wc * 128 + nt * 16 + ln) * 32 + quad * 8);
#pragma unroll
    for (int mt = 0; mt < 4; ++mt)
#pragma unroll
      for (int nt = 0; nt < 8; ++nt)
        acc[mt][nt] = __builtin_amdgcn_mfma_f32_16x16x32_bf16(af[mt], bfr[nt], acc[mt][nt], 0, 0, 0);
    __syncthreads();
  }
  float b2v[8], w3v[8];
#pragma unroll
  for (int nt = 0; nt < 8; ++nt) {
    int n = n0 + wc * 128 + nt * 16 + ln;
    b2v[nt] = b2[n]; w3v[nt] = w3[n];
  }
  if (tid < 128) rowsum[tid] = 0.f;
  __syncthreads();
#pragma unroll
  for (int mt = 0; mt < 4; ++mt) {
    float s[4] = {0.f, 0.f, 0.f, 0.f};
#pragma unroll
    for (int nt = 0; nt < 8; ++nt) {
      f32x4_t c = acc[mt][nt];
#pragma unroll
      for (int r = 0; r < 4; ++r) s[r] += fmaxf(c[r] + b2v[nt], 0.f) * w3v[nt];
    }
#pragma unroll
    for (int r = 0; r < 4; ++r) {
      for (int off = 1; off < 16; off <<= 1) s[r] += __shfl_xor(s[r], off);
      if (ln == 0) atomicAdd(&rowsum[wr * 64 + mt * 16 + quad * 4 + r], s[r]);
    }
  }
  __syncthreads();
  float contrib = 0.f;
  if (tid < 128) {
    float ie = rowsum[tid] + (n0 == 0 ? b3[0] : 0.f);
    int i = i0 + (tid >> 5), j = tid & 31;
    contrib = edges[(size_t)b * 1024 + i * 32 + j] * ie;
  }
  for (int off = 1; off < 64; off <<= 1) contrib += __shfl_xor(contrib, off);
  if (lane == 0 && wave < 2) atomicAdd(&out[b], contrib);
}

extern "C" void kernel_launch(void* const* d_in, const int* in_sizes, int n_in,
                              void* d_out, int out_size, void* d_ws, size_t ws_size,
                              hipStream_t stream) {
  const float* x   = (const float*)d_in[0];
  const float* edges = (const float*)d_in[1];
  const float* t1w = (const float*)d_in[2];
  const float* t1b = (const float*)d_in[3];
  const float* t2w = (const float*)d_in[4];
  const float* t2b = (const float*)d_in[5];
  const float* t3w = (const float*)d_in[6];
  const float* t3b = (const float*)d_in[7];
  const float* i1w = (const float*)d_in[8];
  const float* i1b = (const float*)d_in[9];
  const float* i2w = (const float*)d_in[10];
  const float* i2b = (const float*)d_in[11];
  const float* i3w = (const float*)d_in[12];
  const float* i3b = (const float*)d_in[13];
  char* ws = (char*)d_ws;
  u16*   Xb   = (u16*)(ws + OFF_XB);
  u16*   Wcat = (u16*)(ws + OFF_WCAT);
  u16*   W2t  = (u16*)(ws + OFF_W2T);
  u16*   W2i  = (u16*)(ws + OFF_W2I);
  u16*   T1   = (u16*)(ws + OFF_T1);
  float* Pp   = (float*)(ws + OFF_P);
  float* Qq   = (float*)(ws + OFF_Q);
  float* out  = (float*)d_out;

  hipMemsetAsync(out, 0, 128 * sizeof(float), stream);
  k_prep_x<<<dim3(2, 4096), 256, 0, stream>>>(x, Xb);
  k_prep_wcat<<<dim3(2, 3072), 256, 0, stream>>>(t1w, i1w, Wcat);
  k_transpose<<<dim3(32, 32), dim3(32, 8), 0, stream>>>(t2w, W2t);
  k_transpose<<<dim3(32, 32), dim3(32, 8), 0, stream>>>(i2w, W2i);
  k_gemm_l1<<<dim3(32, 24), 256, 0, stream>>>(Xb, Wcat, t1b, i1b, T1, Pp, Qq);
  k_traj23<<<dim3(32, 8), 256, 0, stream>>>(T1, W2t, t2b, t3w, t3b, out);
  k_int_fused<<<dim3(4, 1024), 256, 0, stream>>>(Pp, Qq, W2i, i2b, i3w, i3b, edges, out);
}

// Round 3
// 584.041 us; speedup vs baseline: 1.6327x; 1.6327x over previous
//
#include <hip/hip_runtime.h>

typedef unsigned short u16;
typedef unsigned int u32;
typedef short bf16x8_t __attribute__((ext_vector_type(8)));
typedef float f32x4_t __attribute__((ext_vector_type(4)));

// ---------------- workspace layout (bytes) ----------------
#define OFF_XB   (0)
#define SZ_XB    (4096*416*2)
#define OFF_WCAT (OFF_XB + SZ_XB)
#define SZ_WCAT  (3072*416*2)
#define OFF_W2T  (OFF_WCAT + SZ_WCAT)
#define SZ_W2    (1024*1024*2)
#define OFF_W2I  (OFF_W2T + SZ_W2)
#define OFF_T1   (OFF_W2I + SZ_W2)
#define SZ_T1    (4096*1024*2)
#define OFF_P    (OFF_T1 + SZ_T1)
#define SZ_PQ    (4096*1024*4)
#define OFF_Q    (OFF_P + SZ_PQ)
// total ~49.7 MB

__device__ __forceinline__ u16 f2bf(float f) {
  union { float f; u32 u; } v; v.f = f;
  u32 r = v.u + 0x7fffu + ((v.u >> 16) & 1u);
  return (u16)(r >> 16);
}
// relu both, round via +0x8000 bias, pack hi16s with one v_perm_b32
__device__ __forceinline__ u32 pk2(float a, float b) {
  u32 ua = __float_as_uint(fmaxf(a, 0.f)) + 0x8000u;
  u32 ub = __float_as_uint(fmaxf(b, 0.f)) + 0x8000u;
  return __builtin_amdgcn_perm(ub, ua, 0x07060302);  // lo16=hi16(ua), hi16=hi16(ub)
}
__device__ __forceinline__ void gload_lds16(const void* g, void* l) {
  __builtin_amdgcn_global_load_lds(
      (const __attribute__((address_space(1))) void*)g,
      (__attribute__((address_space(3))) void*)l, 16, 0, 0);
}

// ---- swizzled staging: LDS[r][s] holds global 16B-chunk (s - r) & 3 of row r.
// Reader of chunk q uses slot (q + r) & 3 -> bank group (5r+q)%8: 2-way = free.
__device__ __forceinline__ void stage_sw(const u16* g, int ld, int row0, int k0,
                                         u16* lds, int nrow64, int wave, int lane) {
  int c = ((lane & 3) - ((lane >> 2) & 3)) & 3;
  const u16* src0 = g + (size_t)(row0 + (lane >> 2)) * ld + k0 + c * 8;
#pragma unroll
  for (int it = 0; it < nrow64; ++it) {
    int rbase = it * 64 + wave * 16;
    gload_lds16(src0 + (size_t)rbase * ld, lds + rbase * 32);
  }
}
__device__ __forceinline__ bf16x8_t read_sw(const u16* lds, int row, int quad) {
  int s = (quad + row) & 3;
  return *(const bf16x8_t*)(lds + row * 32 + s * 8);
}

// ---------------- prep kernels ----------------
__global__ void k_prep_x(const float* __restrict__ x, u16* __restrict__ Xb) {
  int k = blockIdx.x * 256 + threadIdx.x;
  int r = blockIdx.y;
  if (k < 416)
    Xb[(size_t)r * 416 + k] = (k < 400) ? f2bf(x[(size_t)r * 400 + k]) : (u16)0;
}

__global__ void k_prep_wcat(const float* __restrict__ t1w, const float* __restrict__ i1w,
                            u16* __restrict__ Wt) {
  int k = blockIdx.x * 256 + threadIdx.x;
  int n = blockIdx.y;
  if (k >= 416) return;
  float v = 0.f;
  if (k < 400) {
    if (n < 1024)      v = t1w[(size_t)k * 1024 + n];
    else if (n < 2048) v = i1w[(size_t)k * 1024 + (n - 1024)];
    else               v = i1w[(size_t)(400 + k) * 1024 + (n - 2048)];
  }
  Wt[(size_t)n * 416 + k] = f2bf(v);
}

__global__ void k_transpose(const float* __restrict__ W, u16* __restrict__ Wt) {
  __shared__ float t[32][33];
  int k0 = blockIdx.y * 32, n0 = blockIdx.x * 32;
  int tx = threadIdx.x, ty = threadIdx.y;
#pragma unroll
  for (int i = 0; i < 32; i += 8)
    t[ty + i][tx] = W[(size_t)(k0 + ty + i) * 1024 + n0 + tx];
  __syncthreads();
#pragma unroll
  for (int i = 0; i < 32; i += 8)
    Wt[(size_t)(n0 + ty + i) * 1024 + k0 + tx] = f2bf(t[tx][ty + i]);
}

// ---------------- GEMM 1: Xb(4096x416) @ Wcat_t -> T1 | P' | Q ----------------
__global__ __launch_bounds__(256) void k_gemm_l1(
    const u16* __restrict__ Xb, const u16* __restrict__ Wt,
    const float* __restrict__ b_t1, const float* __restrict__ b_i1,
    u16* __restrict__ T1, float* __restrict__ Pp, float* __restrict__ Qq) {
  __shared__ __align__(16) u16 al[128 * 32];
  __shared__ __align__(16) u16 bl[128 * 32];
  int tid = threadIdx.x, lane = tid & 63, wave = tid >> 6;
  int wr = wave & 1, wc = wave >> 1, ln = lane & 15, quad = lane >> 4;
  int m0 = blockIdx.x * 128, n0 = blockIdx.y * 128;
  f32x4_t acc[4][4];
#pragma unroll
  for (int i = 0; i < 4; ++i)
#pragma unroll
    for (int j = 0; j < 4; ++j) acc[i][j] = (f32x4_t){0.f, 0.f, 0.f, 0.f};

  for (int k0 = 0; k0 < 416; k0 += 32) {
    stage_sw(Xb, 416, m0, k0, al, 2, wave, lane);
    stage_sw(Wt, 416, n0, k0, bl, 2, wave, lane);
    __syncthreads();
    bf16x8_t af[4], bfr[4];
#pragma unroll
    for (int mt = 0; mt < 4; ++mt)
      af[mt] = read_sw(al, wr * 64 + mt * 16 + ln, quad);
#pragma unroll
    for (int nt = 0; nt < 4; ++nt)
      bfr[nt] = read_sw(bl, wc * 64 + nt * 16 + ln, quad);
#pragma unroll
    for (int mt = 0; mt < 4; ++mt)
#pragma unroll
      for (int nt = 0; nt < 4; ++nt)
        acc[mt][nt] = __builtin_amdgcn_mfma_f32_16x16x32_bf16(af[mt], bfr[nt], acc[mt][nt], 0, 0, 0);
    __syncthreads();
  }
  int seg = n0 >> 10;  // 0: T1, 1: P'(+b1), 2: Q
#pragma unroll
  for (int nt = 0; nt < 4; ++nt) {
    int n_g = n0 + wc * 64 + nt * 16 + ln;
    int ns = n_g & 1023;
    float bias = (seg == 0) ? b_t1[ns] : (seg == 1 ? b_i1[ns] : 0.f);
#pragma unroll
    for (int mt = 0; mt < 4; ++mt) {
      f32x4_t c = acc[mt][nt];
#pragma unroll
      for (int r = 0; r < 4; ++r) {
        int m_g = m0 + wr * 64 + mt * 16 + quad * 4 + r;
        size_t idx = (size_t)m_g * 1024 + ns;
        float v = c[r] + bias;
        if (seg == 0)      T1[idx] = (u16)((__float_as_uint(fmaxf(v, 0.f)) + 0x8000u) >> 16);
        else if (seg == 1) Pp[idx] = v;
        else               Qq[idx] = v;
      }
    }
  }
}

// ---------------- traj layers 2+3 fused ----------------
__global__ __launch_bounds__(256) void k_traj23(
    const u16* __restrict__ T1, const u16* __restrict__ W2t,
    const float* __restrict__ b2, const float* __restrict__ w3,
    const float* __restrict__ b3, float* __restrict__ out) {
  __shared__ __align__(16) u16 al[128 * 32];
  __shared__ __align__(16) u16 bl[128 * 32];
  __shared__ float rowsum[128];
  int tid = threadIdx.x, lane = tid & 63, wave = tid >> 6;
  int wr = wave & 1, wc = wave >> 1, ln = lane & 15, quad = lane >> 4;
  int m0 = blockIdx.x * 128, n0 = blockIdx.y * 128;
  f32x4_t acc[4][4];
#pragma unroll
  for (int i = 0; i < 4; ++i)
#pragma unroll
    for (int j = 0; j < 4; ++j) acc[i][j] = (f32x4_t){0.f, 0.f, 0.f, 0.f};

  for (int k0 = 0; k0 < 1024; k0 += 32) {
    stage_sw(T1, 1024, m0, k0, al, 2, wave, lane);
    stage_sw(W2t, 1024, n0, k0, bl, 2, wave, lane);
    __syncthreads();
    bf16x8_t af[4], bfr[4];
#pragma unroll
    for (int mt = 0; mt < 4; ++mt)
      af[mt] = read_sw(al, wr * 64 + mt * 16 + ln, quad);
#pragma unroll
    for (int nt = 0; nt < 4; ++nt)
      bfr[nt] = read_sw(bl, wc * 64 + nt * 16 + ln, quad);
#pragma unroll
    for (int mt = 0; mt < 4; ++mt)
#pragma unroll
      for (int nt = 0; nt < 4; ++nt)
        acc[mt][nt] = __builtin_amdgcn_mfma_f32_16x16x32_bf16(af[mt], bfr[nt], acc[mt][nt], 0, 0, 0);
    __syncthreads();
  }
  float b2v[4], w3v[4];
#pragma unroll
  for (int nt = 0; nt < 4; ++nt) {
    int n = n0 + wc * 64 + nt * 16 + ln;
    b2v[nt] = b2[n]; w3v[nt] = w3[n];
  }
  if (tid < 128) rowsum[tid] = 0.f;
  __syncthreads();
#pragma unroll
  for (int mt = 0; mt < 4; ++mt) {
    float s[4] = {0.f, 0.f, 0.f, 0.f};
#pragma unroll
    for (int nt = 0; nt < 4; ++nt) {
      f32x4_t c = acc[mt][nt];
#pragma unroll
      for (int r = 0; r < 4; ++r) s[r] += fmaxf(c[r] + b2v[nt], 0.f) * w3v[nt];
    }
#pragma unroll
    for (int r = 0; r < 4; ++r) {
      for (int off = 1; off < 16; off <<= 1) s[r] += __shfl_xor(s[r], off);
      if (ln == 0) atomicAdd(&rowsum[wr * 64 + mt * 16 + quad * 4 + r], s[r]);
    }
  }
  __syncthreads();
  float contrib = 0.f;
  if (tid < 128) contrib = rowsum[tid] + (n0 == 0 ? b3[0] : 0.f);
  for (int off = 1; off < 32; off <<= 1) contrib += __shfl_xor(contrib, off);
  if ((lane & 31) == 0 && tid < 128) atomicAdd(&out[(m0 + tid) >> 5], contrib);
}

// ---------------- fused interaction: 64m x 256n tile, 4 waves 1x4 ----------------
// acc[4][4] per wave (64 AGPR) keeps 3 blocks/CU; h1 pack per output halves vs 128x128.
#define LDA_H 40
__global__ __launch_bounds__(256) void k_int_fused(
    const float* __restrict__ Pp, const float* __restrict__ Qq,
    const u16* __restrict__ W2t, const float* __restrict__ b2,
    const float* __restrict__ w3, const float* __restrict__ b3,
    const float* __restrict__ edges, float* __restrict__ out) {
  __shared__ __align__(16) u16 h1[64 * LDA_H];
  __shared__ __align__(16) u16 bl[256 * 32];
  __shared__ float rowsum[64];
  int tid = threadIdx.x, lane = tid & 63, wave = tid >> 6;
  int ln = lane & 15, quad = lane >> 4;
  int mtile = blockIdx.y;        // 0..2047 : (b, i0) with 2 i's per tile
  int n0 = blockIdx.x * 256;     // n fastest -> co-resident blocks share P/Q/W2 in L2
  int b = mtile >> 4;
  int i0 = (mtile & 15) * 2;

  int rloc = tid >> 2;           // 0..63 : pair-row within tile
  int kh = (tid & 3) * 8;        // 8 k's per thread
  const float* prow = Pp + ((size_t)(b * 32 + i0 + (rloc >> 5)) << 10) + kh;
  const float* qrow = Qq + ((size_t)(b * 32 + (rloc & 31)) << 10) + kh;

  f32x4_t acc[4][4];
#pragma unroll
  for (int i = 0; i < 4; ++i)
#pragma unroll
    for (int j = 0; j < 4; ++j) acc[i][j] = (f32x4_t){0.f, 0.f, 0.f, 0.f};

  for (int k0 = 0; k0 < 1024; k0 += 32) {
    const float4* pr = (const float4*)(prow + k0);
    const float4* qr = (const float4*)(qrow + k0);
    float4 p0 = pr[0], p1 = pr[1];
    float4 q0 = qr[0], q1 = qr[1];
    uint4 w;
    w.x = pk2(p0.x + q0.x, p0.y + q0.y);
    w.y = pk2(p0.z + q0.z, p0.w + q0.w);
    w.z = pk2(p1.x + q1.x, p1.y + q1.y);
    w.w = pk2(p1.z + q1.z, p1.w + q1.w);
    *(uint4*)(h1 + rloc * LDA_H + kh) = w;
    // stage B tile: 256 rows x 32 cols (swizzled)
    stage_sw(W2t, 1024, n0, k0, bl, 4, wave, lane);
    __syncthreads();
    bf16x8_t af[4], bfr[4];
#pragma unroll
    for (int mt = 0; mt < 4; ++mt)
      af[mt] = *(const bf16x8_t*)(h1 + (mt * 16 + ln) * LDA_H + quad * 8);
#pragma unroll
    for (int nt = 0; nt < 4; ++nt)
      bfr[nt] = read_sw(bl, wave * 64 + nt * 16 + ln, quad);
#pragma unroll
    for (int mt = 0; mt < 4; ++mt)
#pragma unroll
      for (int nt = 0; nt < 4; ++nt)
        acc[mt][nt] = __builtin_amdgcn_mfma_f32_16x16x32_bf16(af[mt], bfr[nt], acc[mt][nt], 0, 0, 0);
    __syncthreads();
  }
  float b2v[4], w3v[4];
#pragma unroll
  for (int nt = 0; nt < 4; ++nt) {
    int n = n0 + wave * 64 + nt * 16 + ln;
    b2v[nt] = b2[n]; w3v[nt] = w3[n];
  }
  if (tid < 64) rowsum[tid] = 0.f;
  __syncthreads();
#pragma unroll
  for (int mt = 0; mt < 4; ++mt) {
    float s[4] = {0.f, 0.f, 0.f, 0.f};
#pragma unroll
    for (int nt = 0; nt < 4; ++nt) {
      f32x4_t c = acc[mt][nt];
#pragma unroll
      for (int r = 0; r < 4; ++r) s[r] += fmaxf(c[r] + b2v[nt], 0.f) * w3v[nt];
    }
#pragma unroll
    for (int r = 0; r < 4; ++r) {
      for (int off = 1; off < 16; off <<= 1) s[r] += __shfl_xor(s[r], off);
      if (ln == 0) atomicAdd(&rowsum[mt * 16 + quad * 4 + r], s[r]);
    }
  }
  __syncthreads();
  if (wave == 0) {
    float ie = rowsum[lane] + (n0 == 0 ? b3[0] : 0.f);
    int i = i0 + (lane >> 5), j = lane & 31;
    float contrib = edges[(size_t)b * 1024 + i * 32 + j] * ie;
    for (int off = 1; off < 64; off <<= 1) contrib += __shfl_xor(contrib, off);
    if (lane == 0) atomicAdd(&out[b], contrib);
  }
}

extern "C" void kernel_launch(void* const* d_in, const int* in_sizes, int n_in,
                              void* d_out, int out_size, void* d_ws, size_t ws_size,
                              hipStream_t stream) {
  const float* x   = (const float*)d_in[0];
  const float* edges = (const float*)d_in[1];
  const float* t1w = (const float*)d_in[2];
  const float* t1b = (const float*)d_in[3];
  const float* t2w = (const float*)d_in[4];
  const float* t2b = (const float*)d_in[5];
  const float* t3w = (const float*)d_in[6];
  const float* t3b = (const float*)d_in[7];
  const float* i1w = (const float*)d_in[8];
  const float* i1b = (const float*)d_in[9];
  const float* i2w = (const float*)d_in[10];
  const float* i2b = (const float*)d_in[11];
  const float* i3w = (const float*)d_in[12];
  const float* i3b = (const float*)d_in[13];
  char* ws = (char*)d_ws;
  u16*   Xb   = (u16*)(ws + OFF_XB);
  u16*   Wcat = (u16*)(ws + OFF_WCAT);
  u16*   W2t  = (u16*)(ws + OFF_W2T);
  u16*   W2i  = (u16*)(ws + OFF_W2I);
  u16*   T1   = (u16*)(ws + OFF_T1);
  float* Pp   = (float*)(ws + OFF_P);
  float* Qq   = (float*)(ws + OFF_Q);
  float* out  = (float*)d_out;

  hipMemsetAsync(out, 0, 128 * sizeof(float), stream);
  k_prep_x<<<dim3(2, 4096), 256, 0, stream>>>(x, Xb);
  k_prep_wcat<<<dim3(2, 3072), 256, 0, stream>>>(t1w, i1w, Wcat);
  k_transpose<<<dim3(32, 32), dim3(32, 8), 0, stream>>>(t2w, W2t);
  k_transpose<<<dim3(32, 32), dim3(32, 8), 0, stream>>>(i2w, W2i);
  k_gemm_l1<<<dim3(32, 24), 256, 0, stream>>>(Xb, Wcat, t1b, i1b, T1, Pp, Qq);
  k_traj23<<<dim3(32, 8), 256, 0, stream>>>(T1, W2t, t2b, t3w, t3b, out);
  k_int_fused<<<dim3(4, 2048), 256, 0, stream>>>(Pp, Qq, W2i, i2b, i3w, i3b, edges, out);
}

// Round 4
// 547.014 us; speedup vs baseline: 1.7432x; 1.0677x over previous
//
#include <hip/hip_runtime.h>

typedef unsigned short u16;
typedef unsigned int u32;
typedef short bf16x8_t __attribute__((ext_vector_type(8)));
typedef float f32x4_t __attribute__((ext_vector_type(4)));

// ---------------- workspace layout (bytes) ----------------
#define OFF_XB   (0)
#define SZ_XB    (4096*416*2)
#define OFF_WCAT (OFF_XB + SZ_XB)
#define SZ_WCAT  (3072*416*2)
#define OFF_W2T  (OFF_WCAT + SZ_WCAT)
#define SZ_W2    (1024*1024*2)
#define OFF_W2I  (OFF_W2T + SZ_W2)
#define OFF_T1   (OFF_W2I + SZ_W2)
#define SZ_T1    (4096*1024*2)
#define OFF_P    (OFF_T1 + SZ_T1)
#define SZ_PQ    (4096*1024*4)
#define OFF_Q    (OFF_P + SZ_PQ)
// total ~49.7 MB

__device__ __forceinline__ u16 f2bf(float f) {
  union { float f; u32 u; } v; v.f = f;
  u32 r = v.u + 0x7fffu + ((v.u >> 16) & 1u);
  return (u16)(r >> 16);
}
// relu both, round via +0x8000 bias, pack hi16s with one v_perm_b32
__device__ __forceinline__ u32 pk2(float a, float b) {
  u32 ua = __float_as_uint(fmaxf(a, 0.f)) + 0x8000u;
  u32 ub = __float_as_uint(fmaxf(b, 0.f)) + 0x8000u;
  return __builtin_amdgcn_perm(ub, ua, 0x07060302);  // lo16=hi16(ua), hi16=hi16(ub)
}
__device__ __forceinline__ void gload_lds16(const void* g, void* l) {
  __builtin_amdgcn_global_load_lds(
      (const __attribute__((address_space(1))) void*)g,
      (__attribute__((address_space(3))) void*)l, 16, 0, 0);
}

// ---- swizzled staging: LDS[r][s] holds global 16B-chunk (s - r) & 3 of row r.
__device__ __forceinline__ void stage_sw(const u16* g, int ld, int row0, int k0,
                                         u16* lds, int nrow64, int wave, int lane) {
  int c = ((lane & 3) - ((lane >> 2) & 3)) & 3;
  const u16* src0 = g + (size_t)(row0 + (lane >> 2)) * ld + k0 + c * 8;
#pragma unroll
  for (int it = 0; it < nrow64; ++it) {
    int rbase = it * 64 + wave * 16;
    gload_lds16(src0 + (size_t)rbase * ld, lds + rbase * 32);
  }
}
__device__ __forceinline__ bf16x8_t read_sw(const u16* lds, int row, int quad) {
  int s = (quad + row) & 3;
  return *(const bf16x8_t*)(lds + row * 32 + s * 8);
}

// ---------------- prep kernels ----------------
__global__ void k_prep_x(const float* __restrict__ x, u16* __restrict__ Xb) {
  int k = blockIdx.x * 256 + threadIdx.x;
  int r = blockIdx.y;
  if (k < 416)
    Xb[(size_t)r * 416 + k] = (k < 400) ? f2bf(x[(size_t)r * 400 + k]) : (u16)0;
}

__global__ void k_prep_wcat(const float* __restrict__ t1w, const float* __restrict__ i1w,
                            u16* __restrict__ Wt) {
  int k = blockIdx.x * 256 + threadIdx.x;
  int n = blockIdx.y;
  if (k >= 416) return;
  float v = 0.f;
  if (k < 400) {
    if (n < 1024)      v = t1w[(size_t)k * 1024 + n];
    else if (n < 2048) v = i1w[(size_t)k * 1024 + (n - 1024)];
    else               v = i1w[(size_t)(400 + k) * 1024 + (n - 2048)];
  }
  Wt[(size_t)n * 416 + k] = f2bf(v);
}

__global__ void k_transpose(const float* __restrict__ W, u16* __restrict__ Wt) {
  __shared__ float t[32][33];
  int k0 = blockIdx.y * 32, n0 = blockIdx.x * 32;
  int tx = threadIdx.x, ty = threadIdx.y;
#pragma unroll
  for (int i = 0; i < 32; i += 8)
    t[ty + i][tx] = W[(size_t)(k0 + ty + i) * 1024 + n0 + tx];
  __syncthreads();
#pragma unroll
  for (int i = 0; i < 32; i += 8)
    Wt[(size_t)(n0 + ty + i) * 1024 + k0 + tx] = f2bf(t[tx][ty + i]);
}

// ---------------- GEMM 1: Xb(4096x416) @ Wcat_t -> T1 | P' | Q ----------------
__global__ __launch_bounds__(256) void k_gemm_l1(
    const u16* __restrict__ Xb, const u16* __restrict__ Wt,
    const float* __restrict__ b_t1, const float* __restrict__ b_i1,
    u16* __restrict__ T1, float* __restrict__ Pp, float* __restrict__ Qq) {
  __shared__ __align__(16) u16 al[128 * 32];
  __shared__ __align__(16) u16 bl[128 * 32];
  int tid = threadIdx.x, lane = tid & 63, wave = tid >> 6;
  int wr = wave & 1, wc = wave >> 1, ln = lane & 15, quad = lane >> 4;
  int m0 = blockIdx.x * 128, n0 = blockIdx.y * 128;
  f32x4_t acc[4][4];
#pragma unroll
  for (int i = 0; i < 4; ++i)
#pragma unroll
    for (int j = 0; j < 4; ++j) acc[i][j] = (f32x4_t){0.f, 0.f, 0.f, 0.f};

  for (int k0 = 0; k0 < 416; k0 += 32) {
    stage_sw(Xb, 416, m0, k0, al, 2, wave, lane);
    stage_sw(Wt, 416, n0, k0, bl, 2, wave, lane);
    __syncthreads();
    bf16x8_t af[4], bfr[4];
#pragma unroll
    for (int mt = 0; mt < 4; ++mt)
      af[mt] = read_sw(al, wr * 64 + mt * 16 + ln, quad);
#pragma unroll
    for (int nt = 0; nt < 4; ++nt)
      bfr[nt] = read_sw(bl, wc * 64 + nt * 16 + ln, quad);
#pragma unroll
    for (int mt = 0; mt < 4; ++mt)
#pragma unroll
      for (int nt = 0; nt < 4; ++nt)
        acc[mt][nt] = __builtin_amdgcn_mfma_f32_16x16x32_bf16(af[mt], bfr[nt], acc[mt][nt], 0, 0, 0);
    __syncthreads();
  }
  int seg = n0 >> 10;  // 0: T1, 1: P'(+b1), 2: Q
#pragma unroll
  for (int nt = 0; nt < 4; ++nt) {
    int n_g = n0 + wc * 64 + nt * 16 + ln;
    int ns = n_g & 1023;
    float bias = (seg == 0) ? b_t1[ns] : (seg == 1 ? b_i1[ns] : 0.f);
#pragma unroll
    for (int mt = 0; mt < 4; ++mt) {
      f32x4_t c = acc[mt][nt];
#pragma unroll
      for (int r = 0; r < 4; ++r) {
        int m_g = m0 + wr * 64 + mt * 16 + quad * 4 + r;
        size_t idx = (size_t)m_g * 1024 + ns;
        float v = c[r] + bias;
        if (seg == 0)      T1[idx] = (u16)((__float_as_uint(fmaxf(v, 0.f)) + 0x8000u) >> 16);
        else if (seg == 1) Pp[idx] = v;
        else               Qq[idx] = v;
      }
    }
  }
}

// ---------------- traj layers 2+3 fused ----------------
__global__ __launch_bounds__(256) void k_traj23(
    const u16* __restrict__ T1, const u16* __restrict__ W2t,
    const float* __restrict__ b2, const float* __restrict__ w3,
    const float* __restrict__ b3, float* __restrict__ out) {
  __shared__ __align__(16) u16 al[128 * 32];
  __shared__ __align__(16) u16 bl[128 * 32];
  __shared__ float rowsum[128];
  int tid = threadIdx.x, lane = tid & 63, wave = tid >> 6;
  int wr = wave & 1, wc = wave >> 1, ln = lane & 15, quad = lane >> 4;
  int m0 = blockIdx.x * 128, n0 = blockIdx.y * 128;
  f32x4_t acc[4][4];
#pragma unroll
  for (int i = 0; i < 4; ++i)
#pragma unroll
    for (int j = 0; j < 4; ++j) acc[i][j] = (f32x4_t){0.f, 0.f, 0.f, 0.f};

  for (int k0 = 0; k0 < 1024; k0 += 32) {
    stage_sw(T1, 1024, m0, k0, al, 2, wave, lane);
    stage_sw(W2t, 1024, n0, k0, bl, 2, wave, lane);
    __syncthreads();
    bf16x8_t af[4], bfr[4];
#pragma unroll
    for (int mt = 0; mt < 4; ++mt)
      af[mt] = read_sw(al, wr * 64 + mt * 16 + ln, quad);
#pragma unroll
    for (int nt = 0; nt < 4; ++nt)
      bfr[nt] = read_sw(bl, wc * 64 + nt * 16 + ln, quad);
#pragma unroll
    for (int mt = 0; mt < 4; ++mt)
#pragma unroll
      for (int nt = 0; nt < 4; ++nt)
        acc[mt][nt] = __builtin_amdgcn_mfma_f32_16x16x32_bf16(af[mt], bfr[nt], acc[mt][nt], 0, 0, 0);
    __syncthreads();
  }
  float b2v[4], w3v[4];
#pragma unroll
  for (int nt = 0; nt < 4; ++nt) {
    int n = n0 + wc * 64 + nt * 16 + ln;
    b2v[nt] = b2[n]; w3v[nt] = w3[n];
  }
  if (tid < 128) rowsum[tid] = 0.f;
  __syncthreads();
#pragma unroll
  for (int mt = 0; mt < 4; ++mt) {
    float s[4] = {0.f, 0.f, 0.f, 0.f};
#pragma unroll
    for (int nt = 0; nt < 4; ++nt) {
      f32x4_t c = acc[mt][nt];
#pragma unroll
      for (int r = 0; r < 4; ++r) s[r] += fmaxf(c[r] + b2v[nt], 0.f) * w3v[nt];
    }
#pragma unroll
    for (int r = 0; r < 4; ++r) {
      for (int off = 1; off < 16; off <<= 1) s[r] += __shfl_xor(s[r], off);
      if (ln == 0) atomicAdd(&rowsum[wr * 64 + mt * 16 + quad * 4 + r], s[r]);
    }
  }
  __syncthreads();
  float contrib = 0.f;
  if (tid < 128) contrib = rowsum[tid] + (n0 == 0 ? b3[0] : 0.f);
  for (int off = 1; off < 32; off <<= 1) contrib += __shfl_xor(contrib, off);
  if ((lane & 31) == 0 && tid < 128) atomicAdd(&out[(m0 + tid) >> 5], contrib);
}

// ---------------- fused interaction: 64m x 256n tile, ping-pong single-barrier K-loop ----
#define LDA_H 40
__global__ __launch_bounds__(256) void k_int_fused(
    const float* __restrict__ Pp, const float* __restrict__ Qq,
    const u16* __restrict__ W2t, const float* __restrict__ b2,
    const float* __restrict__ w3, const float* __restrict__ b3,
    const float* __restrict__ edges, float* __restrict__ out) {
  __shared__ __align__(16) u16 h1[2 * 64 * LDA_H];
  __shared__ __align__(16) u16 bl[2 * 256 * 32];
  __shared__ float rowsum[64];
  int tid = threadIdx.x, lane = tid & 63, wave = tid >> 6;
  int ln = lane & 15, quad = lane >> 4;
  int mtile = blockIdx.y;        // (b, i0): 2 i's x 32 j's = 64 rows
  int n0 = blockIdx.x * 256;     // n fastest -> co-resident blocks share P/Q/W2 in L2
  int b = mtile >> 4;
  int i0 = (mtile & 15) * 2;

  int rloc = tid >> 2;           // 0..63
  int kh = (tid & 3) * 8;        // 8 k's per thread
  const float* prow = Pp + ((size_t)(b * 32 + i0 + (rloc >> 5)) << 10) + kh;
  const float* qrow = Qq + ((size_t)(b * 32 + (rloc & 31)) << 10) + kh;

  f32x4_t acc[4][4];
#pragma unroll
  for (int i = 0; i < 4; ++i)
#pragma unroll
    for (int j = 0; j < 4; ++j) acc[i][j] = (f32x4_t){0.f, 0.f, 0.f, 0.f};

  // ---- prologue: pack k=0 into h1[0], stage B(0) into bl[0], prefetch k=32 ----
  float4 p0, p1, q0, q1;
  {
    const float4* pr = (const float4*)(prow);
    const float4* qr = (const float4*)(qrow);
    p0 = pr[0]; p1 = pr[1]; q0 = qr[0]; q1 = qr[1];
    uint4 w;
    w.x = pk2(p0.x + q0.x, p0.y + q0.y);
    w.y = pk2(p0.z + q0.z, p0.w + q0.w);
    w.z = pk2(p1.x + q1.x, p1.y + q1.y);
    w.w = pk2(p1.z + q1.z, p1.w + q1.w);
    *(uint4*)(h1 + rloc * LDA_H + kh) = w;
    stage_sw(W2t, 1024, n0, 0, bl, 4, wave, lane);
    const float4* prn = (const float4*)(prow + 32);
    const float4* qrn = (const float4*)(qrow + 32);
    p0 = prn[0]; p1 = prn[1]; q0 = qrn[0]; q1 = qrn[1];
  }
  __syncthreads();

  for (int k0 = 0; k0 < 1024; k0 += 32) {
    int cur = (k0 >> 5) & 1, nxt = cur ^ 1;
    u16* h1c = h1 + cur * 64 * LDA_H;
    u16* blc = bl + cur * 256 * 32;
    bf16x8_t af[4], bfr[4];
#pragma unroll
    for (int mt = 0; mt < 4; ++mt)
      af[mt] = *(const bf16x8_t*)(h1c + (mt * 16 + ln) * LDA_H + quad * 8);
#pragma unroll
    for (int nt = 0; nt < 4; ++nt)
      bfr[nt] = read_sw(blc, wave * 64 + nt * 16 + ln, quad);
    // stage next B tile into the other buffer (drained by the end barrier)
    if (k0 + 32 < 1024)
      stage_sw(W2t, 1024, n0, k0 + 32, bl + nxt * 256 * 32, 4, wave, lane);
#pragma unroll
    for (int mt = 0; mt < 4; ++mt)
#pragma unroll
      for (int nt = 0; nt < 4; ++nt)
        acc[mt][nt] = __builtin_amdgcn_mfma_f32_16x16x32_bf16(af[mt], bfr[nt], acc[mt][nt], 0, 0, 0);
    // pack next h1 from prefetched registers; then prefetch one more step ahead
    if (k0 + 32 < 1024) {
      uint4 w;
      w.x = pk2(p0.x + q0.x, p0.y + q0.y);
      w.y = pk2(p0.z + q0.z, p0.w + q0.w);
      w.z = pk2(p1.x + q1.x, p1.y + q1.y);
      w.w = pk2(p1.z + q1.z, p1.w + q1.w);
      *(uint4*)(h1 + nxt * 64 * LDA_H + rloc * LDA_H + kh) = w;
      if (k0 + 64 < 1024) {
        const float4* prn = (const float4*)(prow + k0 + 64);
        const float4* qrn = (const float4*)(qrow + k0 + 64);
        p0 = prn[0]; p1 = prn[1]; q0 = qrn[0]; q1 = qrn[1];
      }
    }
    __syncthreads();
  }

  float b2v[4], w3v[4];
#pragma unroll
  for (int nt = 0; nt < 4; ++nt) {
    int n = n0 + wave * 64 + nt * 16 + ln;
    b2v[nt] = b2[n]; w3v[nt] = w3[n];
  }
  if (tid < 64) rowsum[tid] = 0.f;
  __syncthreads();
#pragma unroll
  for (int mt = 0; mt < 4; ++mt) {
    float s[4] = {0.f, 0.f, 0.f, 0.f};
#pragma unroll
    for (int nt = 0; nt < 4; ++nt) {
      f32x4_t c = acc[mt][nt];
#pragma unroll
      for (int r = 0; r < 4; ++r) s[r] += fmaxf(c[r] + b2v[nt], 0.f) * w3v[nt];
    }
#pragma unroll
    for (int r = 0; r < 4; ++r) {
      for (int off = 1; off < 16; off <<= 1) s[r] += __shfl_xor(s[r], off);
      if (ln == 0) atomicAdd(&rowsum[mt * 16 + quad * 4 + r], s[r]);
    }
  }
  __syncthreads();
  if (wave == 0) {
    float ie = rowsum[lane] + (n0 == 0 ? b3[0] : 0.f);
    int i = i0 + (lane >> 5), j = lane & 31;
    float contrib = edges[(size_t)b * 1024 + i * 32 + j] * ie;
    for (int off = 1; off < 64; off <<= 1) contrib += __shfl_xor(contrib, off);
    if (lane == 0) atomicAdd(&out[b], contrib);
  }
}

extern "C" void kernel_launch(void* const* d_in, const int* in_sizes, int n_in,
                              void* d_out, int out_size, void* d_ws, size_t ws_size,
                              hipStream_t stream) {
  const float* x   = (const float*)d_in[0];
  const float* edges = (const float*)d_in[1];
  const float* t1w = (const float*)d_in[2];
  const float* t1b = (const float*)d_in[3];
  const float* t2w = (const float*)d_in[4];
  const float* t2b = (const float*)d_in[5];
  const float* t3w = (const float*)d_in[6];
  const float* t3b = (const float*)d_in[7];
  const float* i1w = (const float*)d_in[8];
  const float* i1b = (const float*)d_in[9];
  const float* i2w = (const float*)d_in[10];
  const float* i2b = (const float*)d_in[11];
  const float* i3w = (const float*)d_in[12];
  const float* i3b = (const float*)d_in[13];
  char* ws = (char*)d_ws;
  u16*   Xb   = (u16*)(ws + OFF_XB);
  u16*   Wcat = (u16*)(ws + OFF_WCAT);
  u16*   W2t  = (u16*)(ws + OFF_W2T);
  u16*   W2i  = (u16*)(ws + OFF_W2I);
  u16*   T1   = (u16*)(ws + OFF_T1);
  float* Pp   = (float*)(ws + OFF_P);
  float* Qq   = (float*)(ws + OFF_Q);
  float* out  = (float*)d_out;

  hipMemsetAsync(out, 0, 128 * sizeof(float), stream);
  k_prep_x<<<dim3(2, 4096), 256, 0, stream>>>(x, Xb);
  k_prep_wcat<<<dim3(2, 3072), 256, 0, stream>>>(t1w, i1w, Wcat);
  k_transpose<<<dim3(32, 32), dim3(32, 8), 0, stream>>>(t2w, W2t);
  k_transpose<<<dim3(32, 32), dim3(32, 8), 0, stream>>>(i2w, W2i);
  k_gemm_l1<<<dim3(32, 24), 256, 0, stream>>>(Xb, Wcat, t1b, i1b, T1, Pp, Qq);
  k_traj23<<<dim3(32, 8), 256, 0, stream>>>(T1, W2t, t2b, t3w, t3b, out);
  k_int_fused<<<dim3(4, 2048), 256, 0, stream>>>(Pp, Qq, W2i, i2b, i3w, i3b, edges, out);
}